// Round 7
// baseline (219.068 us; speedup 1.0000x reference)
//
#include <hip/hip_runtime.h>
#include <cmath>
#include <cstring>

#define HH 224
#define WW 224
#define CROP 160
#define CI 32
#define CJ 32
#define NCH 384                 // 128*3
#define CH_STRIDE (HH*WW)       // 50176
#define CROP_STRIDE (CROP*CROP) // 25600

// ---- pass-2 (pre-image gather) geometry ----
#define TILE2 32
#define NTIL2 5                 // 5x5 tiles of 32x32
#define GCH2 8                  // channels per block
#define BROWS 46                // phys LDS rows (1 top pad + up to 44 + 1)
#define BHCAP 44                // max staged source rows
#define NG2 14                  // max ushort4 granules per row
#define BSTR 56                 // LDS row stride in floats (14 granules)
// LDS: 2 * 46 * 56 * 4B = 20608 B

// ---- direct-path (fallback) geometry ----
#define TILE 16
#define NTIL 10
#define GCH 8
#define BMAXH 33
#define BMAXW 35
#define LROWS 35
#define LSTR  37
#define LWORDS (LROWS*LSTR)

typedef unsigned short ushort8 __attribute__((ext_vector_type(8)));

struct AugParams {
  float a, b, c, d, e, f, g, h;
  float cosT, sinT;
};

// ---------------------------------------------------------------------------
// Bicubic (Keys a=-0.5) axis weights, matching jax.image.resize.
// ---------------------------------------------------------------------------
__device__ __forceinline__ void axis_weights(int o, float w[4], int id[4]) {
  float s = (o + 0.5f) * (160.0f / 224.0f) - 0.5f;
  int base = (int)floorf(s) - 1;
  float sum = 0.0f;
#pragma unroll
  for (int t = 0; t < 4; ++t) {
    int ii = base + t;
    float dd = fabsf(s - (float)ii);
    float kw;
    if (dd < 1.0f)      kw = ((1.5f * dd - 2.5f) * dd) * dd + 1.0f;
    else if (dd < 2.0f) kw = ((-0.5f * dd + 2.5f) * dd - 4.0f) * dd + 2.0f;
    else                kw = 0.0f;
    if (ii < 0 || ii > CROP - 1) kw = 0.0f;
    w[t] = kw;
    sum += kw;
    id[t] = min(max(ii, 0), CROP - 1);
  }
  float inv = 1.0f / sum;
#pragma unroll
  for (int t = 0; t < 4; ++t) w[t] *= inv;
}

__device__ __forceinline__ float preproc(float v, float nv) {
  float p = (v + 0.45f * nv) * 1.1f;
  return fminf(fmaxf(p, 0.0f), 1.0f);
}

__device__ __forceinline__ float bf2f(unsigned short u) {
  return __uint_as_float(((unsigned int)u) << 16);
}

__device__ __forceinline__ unsigned short f2bf(float f) {
  unsigned int b = __float_as_uint(f);
  return (unsigned short)((b + 0x7fff + ((b >> 16) & 1)) >> 16);
}

// ---------------------------------------------------------------------------
// Pass 1: streaming preproc, fp32 NCHW -> bf16 NCHW.
// Coalesced lane-stride granules; 8 independent 16B loads pinned in flight
// via sched_barrier(0); one 16B store per granule. XCD-chunked block map.
// Grid: 4704 blocks x 256 (exact cover, 8 f32 per thread x 2 granules).
// ---------------------------------------------------------------------------
__global__ __launch_bounds__(256) void preproc_kernel(
    const float4* __restrict__ xin, const float4* __restrict__ nin,
    ushort8* __restrict__ pre) {
  int blk = blockIdx.x;
  blk = (blk & 7) * 588 + (blk >> 3);    // 4704 = 8*588, bijective
  int g0 = blk * 512 + threadIdx.x;      // granule = 8 floats
  int g1 = g0 + 256;
  float4 xa = xin[2 * g0], xb = xin[2 * g0 + 1];
  float4 xc = xin[2 * g1], xd = xin[2 * g1 + 1];
  float4 na = nin[2 * g0], nb = nin[2 * g0 + 1];
  float4 nc = nin[2 * g1], nd = nin[2 * g1 + 1];
  __builtin_amdgcn_sched_barrier(0);     // all 8 loads issued before any use
  ushort8 oa, ob;
  oa[0] = f2bf(preproc(xa.x, na.x)); oa[1] = f2bf(preproc(xa.y, na.y));
  oa[2] = f2bf(preproc(xa.z, na.z)); oa[3] = f2bf(preproc(xa.w, na.w));
  oa[4] = f2bf(preproc(xb.x, nb.x)); oa[5] = f2bf(preproc(xb.y, nb.y));
  oa[6] = f2bf(preproc(xb.z, nb.z)); oa[7] = f2bf(preproc(xb.w, nb.w));
  ob[0] = f2bf(preproc(xc.x, nc.x)); ob[1] = f2bf(preproc(xc.y, nc.y));
  ob[2] = f2bf(preproc(xc.z, nc.z)); ob[3] = f2bf(preproc(xc.w, nc.w));
  ob[4] = f2bf(preproc(xd.x, nd.x)); ob[5] = f2bf(preproc(xd.y, nd.y));
  ob[6] = f2bf(preproc(xd.z, nd.z)); ob[7] = f2bf(preproc(xd.w, nd.w));
  pre[g0] = oa;
  pre[g1] = ob;
}

// ---------------------------------------------------------------------------
// 16 combined taps (global coords, clamped) — fallback paths.
// ---------------------------------------------------------------------------
__device__ __forceinline__ void make_taps(int i, int j, const AugParams P,
                                          int txs[16], int tys[16], float wts[16]) {
  const float cx = (WW - 1) * 0.5f, cy = (HH - 1) * 0.5f;
  float xr = (float)(j + CJ), yr = (float)(i + CI);
  float dx = xr - cx, dy = yr - cy;
  float rx = cx + P.cosT * dx + P.sinT * dy;
  float ry = cy - P.sinT * dx + P.cosT * dy;
  float x0f = floorf(rx), y0f = floorf(ry);
  int x0 = (int)x0f, y0 = (int)y0f;
  float wx1 = rx - x0f, wy1 = ry - y0f;
  float rwx[2] = {1.0f - wx1, wx1};
  float rwy[2] = {1.0f - wy1, wy1};
  int k = 0;
#pragma unroll
  for (int ny = 0; ny < 2; ++ny) {
#pragma unroll
    for (int nx = 0; nx < 2; ++nx) {
      int yn = y0 + ny, xn = x0 + nx;
      bool vn = (xn >= 0 && xn <= WW - 1 && yn >= 0 && yn <= HH - 1);
      float wn = rwy[ny] * rwx[nx] * (vn ? 1.0f : 0.0f);
      float xo = (float)xn, yo = (float)yn;
      float inv = 1.0f / (P.g * xo + P.h * yo + 1.0f);
      float px = (P.a * xo + P.b * yo + P.c) * inv;
      float py = (P.d * xo + P.e * yo + P.f) * inv;
      float px0f = floorf(px), py0f = floorf(py);
      int px0 = (int)px0f, py0 = (int)py0f;
      float pwx1 = px - px0f, pwy1 = py - py0f;
      float pwx[2] = {1.0f - pwx1, pwx1};
      float pwy[2] = {1.0f - pwy1, pwy1};
#pragma unroll
      for (int ty = 0; ty < 2; ++ty) {
#pragma unroll
        for (int tx = 0; tx < 2; ++tx) {
          int yt = py0 + ty, xt = px0 + tx;
          bool vt = (xt >= 0 && xt <= WW - 1 && yt >= 0 && yt <= HH - 1);
          tys[k] = min(max(yt, 0), HH - 1);
          txs[k] = min(max(xt, 0), WW - 1);
          wts[k] = wn * pwy[ty] * pwx[tx] * (vt ? 1.0f : 0.0f);
          ++k;
        }
      }
    }
  }
}

// ---------------------------------------------------------------------------
// Patch origins (phys LDS offsets, BSTR stride) + 16 weights for pixel (i,j).
// ---------------------------------------------------------------------------
__device__ __forceinline__ void make_patches2(int i, int j, const AugParams P,
                                              int by0, int bx0e,
                                              int pofs[4], float wts[16]) {
  const float cx = (WW - 1) * 0.5f, cy = (HH - 1) * 0.5f;
  float xr = (float)(j + CJ), yr = (float)(i + CI);
  float dx = xr - cx, dy = yr - cy;
  float rx = cx + P.cosT * dx + P.sinT * dy;
  float ry = cy - P.sinT * dx + P.cosT * dy;
  float x0f = floorf(rx), y0f = floorf(ry);
  int x0 = (int)x0f, y0 = (int)y0f;
  float wx1 = rx - x0f, wy1 = ry - y0f;
  float rwx[2] = {1.0f - wx1, wx1};
  float rwy[2] = {1.0f - wy1, wy1};
  int n = 0;
#pragma unroll
  for (int ny = 0; ny < 2; ++ny) {
#pragma unroll
    for (int nx = 0; nx < 2; ++nx) {
      int yn = y0 + ny, xn = x0 + nx;
      bool vn = (xn >= 0 && xn <= WW - 1 && yn >= 0 && yn <= HH - 1);
      float wn = rwy[ny] * rwx[nx] * (vn ? 1.0f : 0.0f);
      float xo = (float)xn, yo = (float)yn;
      float inv = 1.0f / (P.g * xo + P.h * yo + 1.0f);
      float px = (P.a * xo + P.b * yo + P.c) * inv;
      float py = (P.d * xo + P.e * yo + P.f) * inv;
      float px0f = floorf(px), py0f = floorf(py);
      int px0 = (int)px0f, py0 = (int)py0f;
      float pwx1 = px - px0f, pwy1 = py - py0f;
      float pwx[2] = {1.0f - pwx1, pwx1};
      float pwy[2] = {1.0f - pwy1, pwy1};
#pragma unroll
      for (int ty = 0; ty < 2; ++ty) {
#pragma unroll
        for (int tx = 0; tx < 2; ++tx) {
          int yt = py0 + ty, xt = px0 + tx;
          bool vt = (xt >= 0 && xt <= WW - 1 && yt >= 0 && yt <= HH - 1);
          wts[n * 4 + ty * 2 + tx] = wn * pwy[ty] * pwx[tx] * (vt ? 1.0f : 0.0f);
        }
      }
      int r0 = py0 - by0 + 1;
      int c0 = px0 - bx0e + 4;
      r0 = min(max(r0, 0), BROWS - 2);
      c0 = min(max(c0, 0), BSTR - 2);
      pofs[n] = r0 * BSTR + c0;
      ++n;
    }
  }
}

// ---------------------------------------------------------------------------
// Pass 2: block = 256 threads = one 32x32 crop tile x 8 channels.
// Tight LDS (20.6KB), 4+ blocks/CU; double-buffered async-split staging;
// taps in registers across channels; XCD-chunked block map.
// ---------------------------------------------------------------------------
__global__ __launch_bounds__(256, 4) void warp_pre_kernel(
    const unsigned short* __restrict__ pre, float* __restrict__ crop,
    AugParams P) {
  __shared__ float s_img[2][BROWS * BSTR];
  int lb = blockIdx.x + blockIdx.y * (NTIL2 * NTIL2);   // 0..1199
  lb = (lb & 7) * 150 + (lb >> 3);                      // 1200 = 8*150
  int tile = lb % (NTIL2 * NTIL2);
  int ch0  = (lb / (NTIL2 * NTIL2)) * GCH2;
  int i0 = (tile / NTIL2) * TILE2;
  int j0 = (tile % NTIL2) * TILE2;

  // ---- wave-uniform exact bbox via corner transforms ----
  const float cx = (WW - 1) * 0.5f, cy = (HH - 1) * 0.5f;
  float rxmin = 1e30f, rxmax = -1e30f, rymin = 1e30f, rymax = -1e30f;
#pragma unroll
  for (int c = 0; c < 4; ++c) {
    float xr = (float)(j0 + CJ + ((c & 1) ? TILE2 - 1 : 0));
    float yr = (float)(i0 + CI + ((c & 2) ? TILE2 - 1 : 0));
    float dx = xr - cx, dy = yr - cy;
    float rx = cx + P.cosT * dx + P.sinT * dy;
    float ry = cy - P.sinT * dx + P.cosT * dy;
    rxmin = fminf(rxmin, rx); rxmax = fmaxf(rxmax, rx);
    rymin = fminf(rymin, ry); rymax = fmaxf(rymax, ry);
  }
  float xnlo = floorf(rxmin), xnhi = floorf(rxmax) + 1.0f;
  float ynlo = floorf(rymin), ynhi = floorf(rymax) + 1.0f;
  float pxmin = 1e30f, pxmax = -1e30f, pymin = 1e30f, pymax = -1e30f;
#pragma unroll
  for (int c = 0; c < 4; ++c) {
    float xo = (c & 1) ? xnhi : xnlo;
    float yo = (c & 2) ? ynhi : ynlo;
    float inv = 1.0f / (P.g * xo + P.h * yo + 1.0f);
    float px = (P.a * xo + P.b * yo + P.c) * inv;
    float py = (P.d * xo + P.e * yo + P.f) * inv;
    pxmin = fminf(pxmin, px); pxmax = fmaxf(pxmax, px);
    pymin = fminf(pymin, py); pymax = fmaxf(pymax, py);
  }
  int bx0 = max(0, (int)floorf(pxmin));
  int bx1 = min(WW - 1, (int)floorf(pxmax) + 1);
  int by0 = max(0, (int)floorf(pymin));
  int by1 = min(HH - 1, (int)floorf(pymax) + 1);
  int bx0e = bx0 & ~3;                   // ushort4-aligned left edge
  int bh = by1 - by0 + 1;
  int gmax = (bx1 - bx0e + 4) >> 2;      // last granule index
  bool use_lds = (bh <= BHCAP) && (gmax <= NG2 - 1);

  int tid = threadIdx.x;

  if (use_lds) {
    // per-thread taps for 4 pixels, reused across all channels
    int pofs[4][4]; float wts[4][16];
#pragma unroll
    for (int k = 0; k < 4; ++k) {
      int p = tid + k * 256;
      make_patches2(i0 + (p >> 5), j0 + (p & 31), P, by0, bx0e, pofs[k], wts[k]);
    }

    // zero-init both buffers once (pads/unstaged slots must be finite)
    for (int s = tid; s < 2 * BROWS * BSTR; s += 256)
      ((float*)s_img)[s] = 0.0f;
    __syncthreads();

    int nslots = bh * NG2;
    // prologue: stage channel ch0 into buffer 0
    {
      const unsigned short* pb = pre + (size_t)ch0 * CH_STRIDE;
#pragma unroll
      for (int q = 0; q < 3; ++q) {
        int s = tid + q * 256;
        if (s < nslots) {
          int r = s / NG2, g = s - r * NG2;
          int x = bx0e - 4 + g * 4;
          if (x >= 0 && x <= WW - 4 && g <= gmax) {
            ushort4 v = *(const ushort4*)(pb + (by0 + r) * WW + x);
            *(float4*)&s_img[0][(r + 1) * BSTR + g * 4] =
                make_float4(bf2f(v.x), bf2f(v.y), bf2f(v.z), bf2f(v.w));
          }
        }
      }
      __syncthreads();
    }

    int buf = 0;
    for (int cc = 0; cc < GCH2; ++cc) {
      int ch = ch0 + cc;
      bool more = (cc < GCH2 - 1);
      // issue next channel's loads early
      ushort4 xv[3];
      if (more) {
        const unsigned short* pb = pre + (size_t)(ch + 1) * CH_STRIDE;
#pragma unroll
        for (int q = 0; q < 3; ++q) {
          int s = tid + q * 256;
          if (s < nslots) {
            int r = s / NG2, g = s - r * NG2;
            int x = bx0e - 4 + g * 4;
            if (x >= 0 && x <= WW - 4 && g <= gmax)
              xv[q] = *(const ushort4*)(pb + (by0 + r) * WW + x);
          }
        }
      }
      // gather current channel from LDS
      const float* sb = s_img[buf];
      float* cb = crop + (size_t)ch * CROP_STRIDE;
#pragma unroll
      for (int k = 0; k < 4; ++k) {
        int p = tid + k * 256;
        float acc = 0.0f;
#pragma unroll
        for (int n = 0; n < 4; ++n) {
          int o = pofs[k][n];
          float v00 = sb[o],        v01 = sb[o + 1];
          float v10 = sb[o + BSTR], v11 = sb[o + BSTR + 1];
          acc = fmaf(wts[k][n * 4 + 0], v00, acc);
          acc = fmaf(wts[k][n * 4 + 1], v01, acc);
          acc = fmaf(wts[k][n * 4 + 2], v10, acc);
          acc = fmaf(wts[k][n * 4 + 3], v11, acc);
        }
        cb[i0 * CROP + (p >> 5) * CROP + j0 + (p & 31)] = acc;
      }
      // write staged next channel into the other buffer
      if (more) {
        float* sw = s_img[buf ^ 1];
#pragma unroll
        for (int q = 0; q < 3; ++q) {
          int s = tid + q * 256;
          if (s < nslots) {
            int r = s / NG2, g = s - r * NG2;
            int x = bx0e - 4 + g * 4;
            if (x >= 0 && x <= WW - 4 && g <= gmax) {
              *(float4*)&sw[(r + 1) * BSTR + g * 4] =
                  make_float4(bf2f(xv[q].x), bf2f(xv[q].y),
                              bf2f(xv[q].z), bf2f(xv[q].w));
            }
          }
        }
      }
      __syncthreads();
      buf ^= 1;
    }
  } else {
    // safety: direct gather from pre (L3-resident)
    for (int k = 0; k < 4; ++k) {
      int p = tid + k * 256;
      int i = i0 + (p >> 5), j = j0 + (p & 31);
      int txs[16], tys[16]; float w[16];
      make_taps(i, j, P, txs, tys, w);
      for (int cc = 0; cc < GCH2; ++cc) {
        int ch = ch0 + cc;
        const unsigned short* pb = pre + (size_t)ch * CH_STRIDE;
        float acc = 0.0f;
#pragma unroll
        for (int t = 0; t < 16; ++t)
          acc = fmaf(w[t], bf2f(pb[tys[t] * WW + txs[t]]), acc);
        crop[(size_t)ch * CROP_STRIDE + i * CROP + j] = acc;
      }
    }
  }
}

// ---------------------------------------------------------------------------
// Direct-path warp kernel (fallback when ws can't fit pre).
// ---------------------------------------------------------------------------
__device__ __forceinline__ void make_patches(int i, int j, const AugParams P,
                                             int by0, int bx0, int bh, int bw,
                                             int pofs[4], float wts[16]) {
  const float cx = (WW - 1) * 0.5f, cy = (HH - 1) * 0.5f;
  float xr = (float)(j + CJ), yr = (float)(i + CI);
  float dx = xr - cx, dy = yr - cy;
  float rx = cx + P.cosT * dx + P.sinT * dy;
  float ry = cy - P.sinT * dx + P.cosT * dy;
  float x0f = floorf(rx), y0f = floorf(ry);
  int x0 = (int)x0f, y0 = (int)y0f;
  float wx1 = rx - x0f, wy1 = ry - y0f;
  float rwx[2] = {1.0f - wx1, wx1};
  float rwy[2] = {1.0f - wy1, wy1};
  int n = 0;
#pragma unroll
  for (int ny = 0; ny < 2; ++ny) {
#pragma unroll
    for (int nx = 0; nx < 2; ++nx) {
      int yn = y0 + ny, xn = x0 + nx;
      bool vn = (xn >= 0 && xn <= WW - 1 && yn >= 0 && yn <= HH - 1);
      float wn = rwy[ny] * rwx[nx] * (vn ? 1.0f : 0.0f);
      float xo = (float)xn, yo = (float)yn;
      float inv = 1.0f / (P.g * xo + P.h * yo + 1.0f);
      float px = (P.a * xo + P.b * yo + P.c) * inv;
      float py = (P.d * xo + P.e * yo + P.f) * inv;
      float px0f = floorf(px), py0f = floorf(py);
      int px0 = (int)px0f, py0 = (int)py0f;
      float pwx1 = px - px0f, pwy1 = py - py0f;
      float pwx[2] = {1.0f - pwx1, pwx1};
      float pwy[2] = {1.0f - pwy1, pwy1};
#pragma unroll
      for (int ty = 0; ty < 2; ++ty) {
#pragma unroll
        for (int tx = 0; tx < 2; ++tx) {
          int yt = py0 + ty, xt = px0 + tx;
          bool vt = (xt >= 0 && xt <= WW - 1 && yt >= 0 && yt <= HH - 1);
          wts[n * 4 + ty * 2 + tx] = wn * pwy[ty] * pwx[tx] * (vt ? 1.0f : 0.0f);
        }
      }
      int ly = py0 - by0;
      int lx = px0 - bx0;
      if (ly < -1 || ly > bh - 1) ly = 0;
      if (lx < -1 || lx > bw - 1) lx = 0;
      pofs[n] = (ly + 1) * LSTR + (lx + 1);
      ++n;
    }
  }
}

__global__ __launch_bounds__(256) void warp_direct_kernel(
    const float* __restrict__ xin, const float* __restrict__ nin,
    float* __restrict__ crop, AugParams P) {
  __shared__ float s_img[2][LWORDS];
  int tile = blockIdx.x;
  int ch0  = blockIdx.y * GCH;
  int i0 = (tile / NTIL) * TILE;
  int j0 = (tile % NTIL) * TILE;

  const float cx = (WW - 1) * 0.5f, cy = (HH - 1) * 0.5f;
  float rxmin = 1e30f, rxmax = -1e30f, rymin = 1e30f, rymax = -1e30f;
#pragma unroll
  for (int c = 0; c < 4; ++c) {
    float xr = (float)(j0 + CJ + ((c & 1) ? TILE - 1 : 0));
    float yr = (float)(i0 + CI + ((c & 2) ? TILE - 1 : 0));
    float dx = xr - cx, dy = yr - cy;
    float rx = cx + P.cosT * dx + P.sinT * dy;
    float ry = cy - P.sinT * dx + P.cosT * dy;
    rxmin = fminf(rxmin, rx); rxmax = fmaxf(rxmax, rx);
    rymin = fminf(rymin, ry); rymax = fmaxf(rymax, ry);
  }
  float xnlo = floorf(rxmin), xnhi = floorf(rxmax) + 1.0f;
  float ynlo = floorf(rymin), ynhi = floorf(rymax) + 1.0f;
  float pxmin = 1e30f, pxmax = -1e30f, pymin = 1e30f, pymax = -1e30f;
#pragma unroll
  for (int c = 0; c < 4; ++c) {
    float xo = (c & 1) ? xnhi : xnlo;
    float yo = (c & 2) ? ynhi : ynlo;
    float inv = 1.0f / (P.g * xo + P.h * yo + 1.0f);
    float px = (P.a * xo + P.b * yo + P.c) * inv;
    float py = (P.d * xo + P.e * yo + P.f) * inv;
    pxmin = fminf(pxmin, px); pxmax = fmaxf(pxmax, px);
    pymin = fminf(pymin, py); pymax = fmaxf(pymax, py);
  }
  int bx0 = max(0, (int)floorf(pxmin));
  int bx1 = min(WW - 1, (int)floorf(pxmax) + 1);
  int by0 = max(0, (int)floorf(pymin));
  int by1 = min(HH - 1, (int)floorf(pymax) + 1);
  int bw = bx1 - bx0 + 1;
  int bh = by1 - by0 + 1;
  bool use_lds = (bw <= BMAXW && bh <= BMAXH);

  int tid = threadIdx.x;
  int i = i0 + (tid >> 4);
  int j = j0 + (tid & 15);
  int opix = i * CROP + j;

  if (use_lds) {
    int pofs[4]; float wts[16];
    make_patches(i, j, P, by0, bx0, bh, bw, pofs, wts);
    for (int s = tid; s < 2 * LWORDS; s += 256)
      ((float*)s_img)[s] = 0.0f;
    __syncthreads();
    {
      const float* xb = xin + (size_t)ch0 * CH_STRIDE;
      const float* nb = nin + (size_t)ch0 * CH_STRIDE;
      int r = tid >> 5, c = tid & 31;
#pragma unroll
      for (int rr = 0; rr < 5; ++rr) {
        int rcur = r + rr * 8;
        if (rcur < bh && c < bw) {
          int g = (by0 + rcur) * WW + bx0 + c;
          s_img[0][(rcur + 1) * LSTR + (c + 1)] = preproc(xb[g], nb[g]);
        }
      }
      if (bw > 32) {
        int r2 = tid >> 2, c2 = 32 + (tid & 3);
        if (r2 < bh && c2 < bw) {
          int g = (by0 + r2) * WW + bx0 + c2;
          s_img[0][(r2 + 1) * LSTR + (c2 + 1)] = preproc(xb[g], nb[g]);
        }
      }
      __syncthreads();
    }
    int buf = 0;
    int r = tid >> 5, c = tid & 31;
    int r2 = tid >> 2, c2 = 32 + (tid & 3);
    for (int cc = 0; cc < GCH; ++cc) {
      int ch = ch0 + cc;
      bool more = (cc < GCH - 1);
      float xv[5], nv[5], xe = 0.0f, ne = 0.0f;
      if (more) {
        const float* xb = xin + (size_t)(ch + 1) * CH_STRIDE;
        const float* nb = nin + (size_t)(ch + 1) * CH_STRIDE;
#pragma unroll
        for (int rr = 0; rr < 5; ++rr) {
          int rcur = r + rr * 8;
          if (rcur < bh && c < bw) {
            int g = (by0 + rcur) * WW + bx0 + c;
            xv[rr] = xb[g]; nv[rr] = nb[g];
          }
        }
        if (bw > 32 && r2 < bh && c2 < bw) {
          int g = (by0 + r2) * WW + bx0 + c2;
          xe = xb[g]; ne = nb[g];
        }
      }
      const float* sb = s_img[buf];
      float acc = 0.0f;
#pragma unroll
      for (int n = 0; n < 4; ++n) {
        int p = pofs[n];
        acc = fmaf(wts[n * 4 + 0], sb[p], acc);
        acc = fmaf(wts[n * 4 + 1], sb[p + 1], acc);
        acc = fmaf(wts[n * 4 + 2], sb[p + LSTR], acc);
        acc = fmaf(wts[n * 4 + 3], sb[p + LSTR + 1], acc);
      }
      crop[(size_t)ch * CROP_STRIDE + opix] = acc;
      if (more) {
        float* sw = s_img[buf ^ 1];
#pragma unroll
        for (int rr = 0; rr < 5; ++rr) {
          int rcur = r + rr * 8;
          if (rcur < bh && c < bw)
            sw[(rcur + 1) * LSTR + (c + 1)] = preproc(xv[rr], nv[rr]);
        }
        if (bw > 32 && r2 < bh && c2 < bw)
          sw[(r2 + 1) * LSTR + (c2 + 1)] = preproc(xe, ne);
      }
      __syncthreads();
      buf ^= 1;
    }
  } else {
    int txs[16], tys[16]; float wts[16];
    make_taps(i, j, P, txs, tys, wts);
    for (int cc = 0; cc < GCH; ++cc) {
      int ch = ch0 + cc;
      const float* xb = xin + (size_t)ch * CH_STRIDE;
      const float* nb = nin + (size_t)ch * CH_STRIDE;
      float acc = 0.0f;
#pragma unroll
      for (int t = 0; t < 16; ++t) {
        int g = tys[t] * WW + txs[t];
        acc = fmaf(wts[t], preproc(xb[g], nb[g]), acc);
      }
      crop[(size_t)ch * CROP_STRIDE + opix] = acc;
    }
  }
}

// ---------------------------------------------------------------------------
// Resize: separable bicubic 160->224, strip per (channel, 28 rows).
// Table computed in-kernel into LDS (no table kernel / global tables).
// ---------------------------------------------------------------------------
#define STRIPROWS 28
#define HROWS 25
__global__ __launch_bounds__(256) void resize_strips_kernel(
    const float* __restrict__ crop, float* __restrict__ out) {
  __shared__ float hbuf[HROWS * WW];
  __shared__ float4 swt[HH];
  __shared__ int4 sit[HH];
  int s = blockIdx.x;
  int ch = blockIdx.y;
  int r0 = max(0, s * 20 - 2);
  const float* cb = crop + (size_t)ch * CROP_STRIDE;
  int tid = threadIdx.x;

  if (tid < HH) {
    float w[4]; int id[4];
    axis_weights(tid, w, id);
    swt[tid] = make_float4(w[0], w[1], w[2], w[3]);
    sit[tid] = make_int4(id[0], id[1], id[2], id[3]);
  }
  __syncthreads();

  for (int e = tid; e < HROWS * WW; e += 256) {
    int r = e / WW;
    int xo = e - r * WW;
    int cr = min(r0 + r, CROP - 1);
    float4 wx = swt[xo]; int4 ix = sit[xo];
    const float* row = cb + cr * CROP;
    hbuf[e] = wx.x * row[ix.x] + wx.y * row[ix.y] +
              wx.z * row[ix.z] + wx.w * row[ix.w];
  }
  __syncthreads();
  for (int e = tid; e < STRIPROWS * WW; e += 256) {
    int yl = e / WW;
    int xo = e - yl * WW;
    int yo = s * STRIPROWS + yl;
    float4 wy = swt[yo]; int4 iy = sit[yo];
    float o = wy.x * hbuf[(iy.x - r0) * WW + xo] +
              wy.y * hbuf[(iy.y - r0) * WW + xo] +
              wy.z * hbuf[(iy.z - r0) * WW + xo] +
              wy.w * hbuf[(iy.w - r0) * WW + xo];
    __builtin_nontemporal_store(o, &out[((size_t)ch * HH + yo) * WW + xo]);
  }
}

// ---------------------------------------------------------------------------
// Fully fused fallback (tiny ws).
// ---------------------------------------------------------------------------
__device__ float crop_val(const float* __restrict__ xb, const float* __restrict__ nb,
                          int i, int j, AugParams P) {
  int txs[16], tys[16]; float wts[16];
  make_taps(i, j, P, txs, tys, wts);
  float acc = 0.0f;
#pragma unroll
  for (int t = 0; t < 16; ++t)
    acc = fmaf(wts[t], preproc(xb[tys[t] * WW + txs[t]], nb[tys[t] * WW + txs[t]]), acc);
  return acc;
}

__global__ __launch_bounds__(256) void fused_fallback_kernel(
    const float* __restrict__ xin, const float* __restrict__ nin,
    float* __restrict__ out, AugParams P, int total) {
  int stride = gridDim.x * blockDim.x;
  for (int idx = blockIdx.x * blockDim.x + threadIdx.x; idx < total; idx += stride) {
    int xo = idx % WW;
    int t2 = idx / WW;
    int yo = t2 % HH;
    int ch = t2 / HH;
    float wxa[4]; int ixa[4]; axis_weights(xo, wxa, ixa);
    float wya[4]; int iya[4]; axis_weights(yo, wya, iya);
    const float* xb = xin + (size_t)ch * CH_STRIDE;
    const float* nb = nin + (size_t)ch * CH_STRIDE;
    float acc = 0.0f;
#pragma unroll
    for (int ty = 0; ty < 4; ++ty)
#pragma unroll
      for (int tx = 0; tx < 4; ++tx)
        acc += wya[ty] * wxa[tx] * crop_val(xb, nb, iya[ty], ixa[tx], P);
    out[idx] = acc;
  }
}

// ---------------------------------------------------------------------------
// Host: solve 8x8 perspective system.
// ---------------------------------------------------------------------------
static void solve_coeffs(double C[8]) {
  const double sp[4][2] = {{0, 0}, {223, 0}, {223, 223}, {0, 223}};
  const double ep[4][2] = {{30, 20}, {200, 25}, {210, 200}, {15, 190}};
  double A[8][9];
  for (int k = 0; k < 4; ++k) {
    double xi = sp[k][0], yi = sp[k][1], xo = ep[k][0], yo = ep[k][1];
    double r0[9] = {xo, yo, 1, 0, 0, 0, -xo * xi, -yo * xi, xi};
    double r1[9] = {0, 0, 0, xo, yo, 1, -xo * yi, -yo * yi, yi};
    std::memcpy(A[2 * k], r0, sizeof r0);
    std::memcpy(A[2 * k + 1], r1, sizeof r1);
  }
  for (int col = 0; col < 8; ++col) {
    int piv = col;
    for (int r = col + 1; r < 8; ++r)
      if (std::fabs(A[r][col]) > std::fabs(A[piv][col])) piv = r;
    if (piv != col)
      for (int cc = 0; cc < 9; ++cc) { double t = A[col][cc]; A[col][cc] = A[piv][cc]; A[piv][cc] = t; }
    double p = A[col][col];
    for (int r = 0; r < 8; ++r) {
      if (r == col) continue;
      double fmul = A[r][col] / p;
      for (int cc = col; cc < 9; ++cc) A[r][cc] -= fmul * A[col][cc];
    }
  }
  for (int r = 0; r < 8; ++r) C[r] = A[r][8] / A[r][r];
}

extern "C" void kernel_launch(void* const* d_in, const int* in_sizes, int n_in,
                              void* d_out, int out_size, void* d_ws, size_t ws_size,
                              hipStream_t stream) {
  const float* xin = (const float*)d_in[0];
  const float* nin = (const float*)d_in[1];
  float* out = (float*)d_out;

  double C[8];
  solve_coeffs(C);
  AugParams P;
  P.a = (float)C[0]; P.b = (float)C[1]; P.c = (float)C[2]; P.d = (float)C[3];
  P.e = (float)C[4]; P.f = (float)C[5]; P.g = (float)C[6]; P.h = (float)C[7];
  double t = 10.0 * M_PI / 180.0;
  P.cosT = (float)std::cos(t);
  P.sinT = (float)std::sin(t);

  const int total = NCH * HH * WW;                 // 19,267,584
  const size_t PRE_BYTES = (size_t)NCH * CH_STRIDE * 2;      // 38,535,168
  const size_t CROP_BYTES = (size_t)NCH * CROP_STRIDE * 4;   // 39,321,600
  const size_t need_full = PRE_BYTES + CROP_BYTES;
  const size_t need_med = CROP_BYTES;

  if (ws_size >= need_full) {
    unsigned short* pre = (unsigned short*)d_ws;
    float* crop = (float*)((char*)d_ws + PRE_BYTES);

    hipLaunchKernelGGL(preproc_kernel, dim3(4704), dim3(256), 0, stream,
                       (const float4*)xin, (const float4*)nin, (ushort8*)pre);
    dim3 g1(NTIL2 * NTIL2, NCH / GCH2);            // (25, 48)
    hipLaunchKernelGGL(warp_pre_kernel, g1, dim3(256), 0, stream, pre, crop, P);
    dim3 g2(HH / STRIPROWS, NCH);                  // (8, 384)
    hipLaunchKernelGGL(resize_strips_kernel, g2, dim3(256), 0, stream, crop, out);
  } else if (ws_size >= need_med) {
    float* crop = (float*)d_ws;

    dim3 g1(NTIL * NTIL, NCH / GCH);               // (100, 48)
    hipLaunchKernelGGL(warp_direct_kernel, g1, dim3(256), 0, stream, xin, nin, crop, P);
    dim3 g2(HH / STRIPROWS, NCH);
    hipLaunchKernelGGL(resize_strips_kernel, g2, dim3(256), 0, stream, crop, out);
  } else {
    hipLaunchKernelGGL(fused_fallback_kernel, dim3(2048), dim3(256), 0, stream,
                       xin, nin, out, P, total);
  }
}

// Round 8
// 102.700 us; speedup vs baseline: 2.1331x; 2.1331x over previous
//
#include <hip/hip_runtime.h>
#include <cmath>
#include <cstring>

#define HH 224
#define WW 224
#define CROP 160
#define CI 32
#define CJ 32
#define NCH 384                 // 128*3
#define CH_STRIDE (HH*WW)       // 50176
#define CROP_STRIDE (CROP*CROP) // 25600

// ---- pass-2 (pre-image gather) geometry (R6-proven; caps verified vs
// measured inverse-map gradients: max bh ~60 <= 62, max granule ~16 <= 17) ----
#define TILE2 32
#define NTIL2 5                 // 5x5 tiles of 32x32
#define GCH2 8                  // channels per block
#define BH2 64                  // phys LDS rows (row0 = logical -1 pad)
#define BHCAP 62                // max staged source rows
#define NG2 18                  // max ushort4 granules per row
#define BSTR 80                 // LDS row stride in floats (16B-aligned granules)
// LDS: 2 * 64 * 80 * 4B = 40960 B -> 3 blocks/CU

// ---- direct-path (fallback) geometry ----
#define TILE 16
#define NTIL 10
#define GCH 8
#define BMAXH 33
#define BMAXW 35
#define LROWS 35
#define LSTR  37
#define LWORDS (LROWS*LSTR)

typedef unsigned short ushort8 __attribute__((ext_vector_type(8)));

struct AugParams {
  float a, b, c, d, e, f, g, h;
  float cosT, sinT;
};

// ---------------------------------------------------------------------------
// Bicubic (Keys a=-0.5) axis weights, matching jax.image.resize.
// ---------------------------------------------------------------------------
__device__ __forceinline__ void axis_weights(int o, float w[4], int id[4]) {
  float s = (o + 0.5f) * (160.0f / 224.0f) - 0.5f;
  int base = (int)floorf(s) - 1;
  float sum = 0.0f;
#pragma unroll
  for (int t = 0; t < 4; ++t) {
    int ii = base + t;
    float dd = fabsf(s - (float)ii);
    float kw;
    if (dd < 1.0f)      kw = ((1.5f * dd - 2.5f) * dd) * dd + 1.0f;
    else if (dd < 2.0f) kw = ((-0.5f * dd + 2.5f) * dd - 4.0f) * dd + 2.0f;
    else                kw = 0.0f;
    if (ii < 0 || ii > CROP - 1) kw = 0.0f;
    w[t] = kw;
    sum += kw;
    id[t] = min(max(ii, 0), CROP - 1);
  }
  float inv = 1.0f / sum;
#pragma unroll
  for (int t = 0; t < 4; ++t) w[t] *= inv;
}

__device__ __forceinline__ float preproc(float v, float nv) {
  float p = (v + 0.45f * nv) * 1.1f;
  return fminf(fmaxf(p, 0.0f), 1.0f);
}

__device__ __forceinline__ float bf2f(unsigned short u) {
  return __uint_as_float(((unsigned int)u) << 16);
}

__device__ __forceinline__ unsigned short f2bf(float f) {
  unsigned int b = __float_as_uint(f);
  return (unsigned short)((b + 0x7fff + ((b >> 16) & 1)) >> 16);
}

// ---------------------------------------------------------------------------
// Pass 1: streaming preproc, fp32 NCHW -> bf16 NCHW (R7 version, kept).
// Coalesced lane-stride granules; 8 independent 16B loads pinned in flight
// via sched_barrier(0); 16B stores. XCD-chunked block map.
// ---------------------------------------------------------------------------
__global__ __launch_bounds__(256) void preproc_kernel(
    const float4* __restrict__ xin, const float4* __restrict__ nin,
    ushort8* __restrict__ pre) {
  int blk = blockIdx.x;
  blk = (blk & 7) * 588 + (blk >> 3);    // 4704 = 8*588, bijective
  int g0 = blk * 512 + threadIdx.x;      // granule = 8 floats
  int g1 = g0 + 256;
  float4 xa = xin[2 * g0], xb = xin[2 * g0 + 1];
  float4 xc = xin[2 * g1], xd = xin[2 * g1 + 1];
  float4 na = nin[2 * g0], nb = nin[2 * g0 + 1];
  float4 nc = nin[2 * g1], nd = nin[2 * g1 + 1];
  __builtin_amdgcn_sched_barrier(0);     // all 8 loads issued before any use
  ushort8 oa, ob;
  oa[0] = f2bf(preproc(xa.x, na.x)); oa[1] = f2bf(preproc(xa.y, na.y));
  oa[2] = f2bf(preproc(xa.z, na.z)); oa[3] = f2bf(preproc(xa.w, na.w));
  oa[4] = f2bf(preproc(xb.x, nb.x)); oa[5] = f2bf(preproc(xb.y, nb.y));
  oa[6] = f2bf(preproc(xb.z, nb.z)); oa[7] = f2bf(preproc(xb.w, nb.w));
  ob[0] = f2bf(preproc(xc.x, nc.x)); ob[1] = f2bf(preproc(xc.y, nc.y));
  ob[2] = f2bf(preproc(xc.z, nc.z)); ob[3] = f2bf(preproc(xc.w, nc.w));
  ob[4] = f2bf(preproc(xd.x, nd.x)); ob[5] = f2bf(preproc(xd.y, nd.y));
  ob[6] = f2bf(preproc(xd.z, nd.z)); ob[7] = f2bf(preproc(xd.w, nd.w));
  pre[g0] = oa;
  pre[g1] = ob;
}

// ---------------------------------------------------------------------------
// 16 combined taps (global coords, clamped) — fallback paths.
// ---------------------------------------------------------------------------
__device__ __forceinline__ void make_taps(int i, int j, const AugParams P,
                                          int txs[16], int tys[16], float wts[16]) {
  const float cx = (WW - 1) * 0.5f, cy = (HH - 1) * 0.5f;
  float xr = (float)(j + CJ), yr = (float)(i + CI);
  float dx = xr - cx, dy = yr - cy;
  float rx = cx + P.cosT * dx + P.sinT * dy;
  float ry = cy - P.sinT * dx + P.cosT * dy;
  float x0f = floorf(rx), y0f = floorf(ry);
  int x0 = (int)x0f, y0 = (int)y0f;
  float wx1 = rx - x0f, wy1 = ry - y0f;
  float rwx[2] = {1.0f - wx1, wx1};
  float rwy[2] = {1.0f - wy1, wy1};
  int k = 0;
#pragma unroll
  for (int ny = 0; ny < 2; ++ny) {
#pragma unroll
    for (int nx = 0; nx < 2; ++nx) {
      int yn = y0 + ny, xn = x0 + nx;
      bool vn = (xn >= 0 && xn <= WW - 1 && yn >= 0 && yn <= HH - 1);
      float wn = rwy[ny] * rwx[nx] * (vn ? 1.0f : 0.0f);
      float xo = (float)xn, yo = (float)yn;
      float inv = 1.0f / (P.g * xo + P.h * yo + 1.0f);
      float px = (P.a * xo + P.b * yo + P.c) * inv;
      float py = (P.d * xo + P.e * yo + P.f) * inv;
      float px0f = floorf(px), py0f = floorf(py);
      int px0 = (int)px0f, py0 = (int)py0f;
      float pwx1 = px - px0f, pwy1 = py - py0f;
      float pwx[2] = {1.0f - pwx1, pwx1};
      float pwy[2] = {1.0f - pwy1, pwy1};
#pragma unroll
      for (int ty = 0; ty < 2; ++ty) {
#pragma unroll
        for (int tx = 0; tx < 2; ++tx) {
          int yt = py0 + ty, xt = px0 + tx;
          bool vt = (xt >= 0 && xt <= WW - 1 && yt >= 0 && yt <= HH - 1);
          tys[k] = min(max(yt, 0), HH - 1);
          txs[k] = min(max(xt, 0), WW - 1);
          wts[k] = wn * pwy[ty] * pwx[tx] * (vt ? 1.0f : 0.0f);
          ++k;
        }
      }
    }
  }
}

// ---------------------------------------------------------------------------
// Patch origins (phys LDS offsets, BSTR stride) + 16 weights for pixel (i,j).
// ---------------------------------------------------------------------------
__device__ __forceinline__ void make_patches2(int i, int j, const AugParams P,
                                              int by0, int bx0e,
                                              int pofs[4], float wts[16]) {
  const float cx = (WW - 1) * 0.5f, cy = (HH - 1) * 0.5f;
  float xr = (float)(j + CJ), yr = (float)(i + CI);
  float dx = xr - cx, dy = yr - cy;
  float rx = cx + P.cosT * dx + P.sinT * dy;
  float ry = cy - P.sinT * dx + P.cosT * dy;
  float x0f = floorf(rx), y0f = floorf(ry);
  int x0 = (int)x0f, y0 = (int)y0f;
  float wx1 = rx - x0f, wy1 = ry - y0f;
  float rwx[2] = {1.0f - wx1, wx1};
  float rwy[2] = {1.0f - wy1, wy1};
  int n = 0;
#pragma unroll
  for (int ny = 0; ny < 2; ++ny) {
#pragma unroll
    for (int nx = 0; nx < 2; ++nx) {
      int yn = y0 + ny, xn = x0 + nx;
      bool vn = (xn >= 0 && xn <= WW - 1 && yn >= 0 && yn <= HH - 1);
      float wn = rwy[ny] * rwx[nx] * (vn ? 1.0f : 0.0f);
      float xo = (float)xn, yo = (float)yn;
      float inv = 1.0f / (P.g * xo + P.h * yo + 1.0f);
      float px = (P.a * xo + P.b * yo + P.c) * inv;
      float py = (P.d * xo + P.e * yo + P.f) * inv;
      float px0f = floorf(px), py0f = floorf(py);
      int px0 = (int)px0f, py0 = (int)py0f;
      float pwx1 = px - px0f, pwy1 = py - py0f;
      float pwx[2] = {1.0f - pwx1, pwx1};
      float pwy[2] = {1.0f - pwy1, pwy1};
#pragma unroll
      for (int ty = 0; ty < 2; ++ty) {
#pragma unroll
        for (int tx = 0; tx < 2; ++tx) {
          int yt = py0 + ty, xt = px0 + tx;
          bool vt = (xt >= 0 && xt <= WW - 1 && yt >= 0 && yt <= HH - 1);
          wts[n * 4 + ty * 2 + tx] = wn * pwy[ty] * pwx[tx] * (vt ? 1.0f : 0.0f);
        }
      }
      int r0 = py0 - by0 + 1;
      int c0 = px0 - bx0e + 4;
      r0 = min(max(r0, 0), BH2 - 2);
      c0 = min(max(c0, 0), BSTR - 2);
      pofs[n] = r0 * BSTR + c0;
      ++n;
    }
  }
}

// ---------------------------------------------------------------------------
// Pass 2 (R6-proven geometry): block = 256 threads = one 32x32 crop tile x
// 8 channels. bf16 pre bbox staged via ushort4 loads -> float4 ds_write_b128
// into 16B-aligned LDS granules; double-buffered async-split; taps in regs.
// ---------------------------------------------------------------------------
__global__ __launch_bounds__(256, 3) void warp_pre_kernel(
    const unsigned short* __restrict__ pre, float* __restrict__ crop,
    AugParams P) {
  __shared__ float s_img[2][BH2 * BSTR];
  int tile = blockIdx.x;                 // 0..24
  int ch0  = blockIdx.y * GCH2;
  int i0 = (tile / NTIL2) * TILE2;
  int j0 = (tile % NTIL2) * TILE2;

  // ---- wave-uniform exact bbox via corner transforms ----
  const float cx = (WW - 1) * 0.5f, cy = (HH - 1) * 0.5f;
  float rxmin = 1e30f, rxmax = -1e30f, rymin = 1e30f, rymax = -1e30f;
#pragma unroll
  for (int c = 0; c < 4; ++c) {
    float xr = (float)(j0 + CJ + ((c & 1) ? TILE2 - 1 : 0));
    float yr = (float)(i0 + CI + ((c & 2) ? TILE2 - 1 : 0));
    float dx = xr - cx, dy = yr - cy;
    float rx = cx + P.cosT * dx + P.sinT * dy;
    float ry = cy - P.sinT * dx + P.cosT * dy;
    rxmin = fminf(rxmin, rx); rxmax = fmaxf(rxmax, rx);
    rymin = fminf(rymin, ry); rymax = fmaxf(rymax, ry);
  }
  float xnlo = floorf(rxmin), xnhi = floorf(rxmax) + 1.0f;
  float ynlo = floorf(rymin), ynhi = floorf(rymax) + 1.0f;
  float pxmin = 1e30f, pxmax = -1e30f, pymin = 1e30f, pymax = -1e30f;
#pragma unroll
  for (int c = 0; c < 4; ++c) {
    float xo = (c & 1) ? xnhi : xnlo;
    float yo = (c & 2) ? ynhi : ynlo;
    float inv = 1.0f / (P.g * xo + P.h * yo + 1.0f);
    float px = (P.a * xo + P.b * yo + P.c) * inv;
    float py = (P.d * xo + P.e * yo + P.f) * inv;
    pxmin = fminf(pxmin, px); pxmax = fmaxf(pxmax, px);
    pymin = fminf(pymin, py); pymax = fmaxf(pymax, py);
  }
  int bx0 = max(0, (int)floorf(pxmin));
  int bx1 = min(WW - 1, (int)floorf(pxmax) + 1);
  int by0 = max(0, (int)floorf(pymin));
  int by1 = min(HH - 1, (int)floorf(pymax) + 1);
  int bx0e = bx0 & ~3;                   // ushort4-aligned left edge
  int bh = by1 - by0 + 1;
  int gmax = (bx1 - bx0e + 4) >> 2;      // last granule index
  bool use_lds = (bh <= BHCAP) && (gmax <= NG2 - 1);

  int tid = threadIdx.x;

  if (use_lds) {
    // per-thread taps for 4 pixels, reused across all channels
    int pofs[4][4]; float wts[4][16];
#pragma unroll
    for (int k = 0; k < 4; ++k) {
      int p = tid + k * 256;
      make_patches2(i0 + (p >> 5), j0 + (p & 31), P, by0, bx0e, pofs[k], wts[k]);
    }

    // zero-init both buffers once (pads/unstaged slots must be finite)
    for (int s = tid; s < 2 * BH2 * BSTR; s += 256)
      ((float*)s_img)[s] = 0.0f;
    __syncthreads();

    int nslots = bh * NG2;
    // prologue: stage channel ch0 into buffer 0
    {
      const unsigned short* pb = pre + (size_t)ch0 * CH_STRIDE;
#pragma unroll
      for (int q = 0; q < 5; ++q) {
        int s = tid + q * 256;
        if (s < nslots) {
          int r = s / NG2, g = s - r * NG2;
          int x = bx0e - 4 + g * 4;
          if (x >= 0 && g <= gmax) {
            ushort4 v = *(const ushort4*)(pb + (by0 + r) * WW + x);
            *(float4*)&s_img[0][(r + 1) * BSTR + g * 4] =
                make_float4(bf2f(v.x), bf2f(v.y), bf2f(v.z), bf2f(v.w));
          }
        }
      }
      __syncthreads();
    }

    int buf = 0;
    for (int cc = 0; cc < GCH2; ++cc) {
      int ch = ch0 + cc;
      bool more = (cc < GCH2 - 1);
      // issue next channel's loads early
      ushort4 xv[5];
      if (more) {
        const unsigned short* pb = pre + (size_t)(ch + 1) * CH_STRIDE;
#pragma unroll
        for (int q = 0; q < 5; ++q) {
          int s = tid + q * 256;
          if (s < nslots) {
            int r = s / NG2, g = s - r * NG2;
            int x = bx0e - 4 + g * 4;
            if (x >= 0 && g <= gmax)
              xv[q] = *(const ushort4*)(pb + (by0 + r) * WW + x);
          }
        }
      }
      // gather current channel from LDS
      const float* sb = s_img[buf];
      float* cb = crop + (size_t)ch * CROP_STRIDE;
#pragma unroll
      for (int k = 0; k < 4; ++k) {
        int p = tid + k * 256;
        float acc = 0.0f;
#pragma unroll
        for (int n = 0; n < 4; ++n) {
          int o = pofs[k][n];
          float v00 = sb[o],        v01 = sb[o + 1];
          float v10 = sb[o + BSTR], v11 = sb[o + BSTR + 1];
          acc = fmaf(wts[k][n * 4 + 0], v00, acc);
          acc = fmaf(wts[k][n * 4 + 1], v01, acc);
          acc = fmaf(wts[k][n * 4 + 2], v10, acc);
          acc = fmaf(wts[k][n * 4 + 3], v11, acc);
        }
        cb[i0 * CROP + (p >> 5) * CROP + j0 + (p & 31)] = acc;
      }
      // write staged next channel into the other buffer
      if (more) {
        float* sw = s_img[buf ^ 1];
#pragma unroll
        for (int q = 0; q < 5; ++q) {
          int s = tid + q * 256;
          if (s < nslots) {
            int r = s / NG2, g = s - r * NG2;
            int x = bx0e - 4 + g * 4;
            if (x >= 0 && g <= gmax) {
              *(float4*)&sw[(r + 1) * BSTR + g * 4] =
                  make_float4(bf2f(xv[q].x), bf2f(xv[q].y),
                              bf2f(xv[q].z), bf2f(xv[q].w));
            }
          }
        }
      }
      __syncthreads();
      buf ^= 1;
    }
  } else {
    // safety: direct gather from pre (L3-resident)
    for (int k = 0; k < 4; ++k) {
      int p = tid + k * 256;
      int i = i0 + (p >> 5), j = j0 + (p & 31);
      int txs[16], tys[16]; float w[16];
      make_taps(i, j, P, txs, tys, w);
      for (int cc = 0; cc < GCH2; ++cc) {
        int ch = ch0 + cc;
        const unsigned short* pb = pre + (size_t)ch * CH_STRIDE;
        float acc = 0.0f;
#pragma unroll
        for (int t = 0; t < 16; ++t)
          acc = fmaf(w[t], bf2f(pb[tys[t] * WW + txs[t]]), acc);
        crop[(size_t)ch * CROP_STRIDE + i * CROP + j] = acc;
      }
    }
  }
}

// ---------------------------------------------------------------------------
// Direct-path warp kernel (fallback when ws can't fit pre).
// ---------------------------------------------------------------------------
__device__ __forceinline__ void make_patches(int i, int j, const AugParams P,
                                             int by0, int bx0, int bh, int bw,
                                             int pofs[4], float wts[16]) {
  const float cx = (WW - 1) * 0.5f, cy = (HH - 1) * 0.5f;
  float xr = (float)(j + CJ), yr = (float)(i + CI);
  float dx = xr - cx, dy = yr - cy;
  float rx = cx + P.cosT * dx + P.sinT * dy;
  float ry = cy - P.sinT * dx + P.cosT * dy;
  float x0f = floorf(rx), y0f = floorf(ry);
  int x0 = (int)x0f, y0 = (int)y0f;
  float wx1 = rx - x0f, wy1 = ry - y0f;
  float rwx[2] = {1.0f - wx1, wx1};
  float rwy[2] = {1.0f - wy1, wy1};
  int n = 0;
#pragma unroll
  for (int ny = 0; ny < 2; ++ny) {
#pragma unroll
    for (int nx = 0; nx < 2; ++nx) {
      int yn = y0 + ny, xn = x0 + nx;
      bool vn = (xn >= 0 && xn <= WW - 1 && yn >= 0 && yn <= HH - 1);
      float wn = rwy[ny] * rwx[nx] * (vn ? 1.0f : 0.0f);
      float xo = (float)xn, yo = (float)yn;
      float inv = 1.0f / (P.g * xo + P.h * yo + 1.0f);
      float px = (P.a * xo + P.b * yo + P.c) * inv;
      float py = (P.d * xo + P.e * yo + P.f) * inv;
      float px0f = floorf(px), py0f = floorf(py);
      int px0 = (int)px0f, py0 = (int)py0f;
      float pwx1 = px - px0f, pwy1 = py - py0f;
      float pwx[2] = {1.0f - pwx1, pwx1};
      float pwy[2] = {1.0f - pwy1, pwy1};
#pragma unroll
      for (int ty = 0; ty < 2; ++ty) {
#pragma unroll
        for (int tx = 0; tx < 2; ++tx) {
          int yt = py0 + ty, xt = px0 + tx;
          bool vt = (xt >= 0 && xt <= WW - 1 && yt >= 0 && yt <= HH - 1);
          wts[n * 4 + ty * 2 + tx] = wn * pwy[ty] * pwx[tx] * (vt ? 1.0f : 0.0f);
        }
      }
      int ly = py0 - by0;
      int lx = px0 - bx0;
      if (ly < -1 || ly > bh - 1) ly = 0;
      if (lx < -1 || lx > bw - 1) lx = 0;
      pofs[n] = (ly + 1) * LSTR + (lx + 1);
      ++n;
    }
  }
}

__global__ __launch_bounds__(256) void warp_direct_kernel(
    const float* __restrict__ xin, const float* __restrict__ nin,
    float* __restrict__ crop, AugParams P) {
  __shared__ float s_img[2][LWORDS];
  int tile = blockIdx.x;
  int ch0  = blockIdx.y * GCH;
  int i0 = (tile / NTIL) * TILE;
  int j0 = (tile % NTIL) * TILE;

  const float cx = (WW - 1) * 0.5f, cy = (HH - 1) * 0.5f;
  float rxmin = 1e30f, rxmax = -1e30f, rymin = 1e30f, rymax = -1e30f;
#pragma unroll
  for (int c = 0; c < 4; ++c) {
    float xr = (float)(j0 + CJ + ((c & 1) ? TILE - 1 : 0));
    float yr = (float)(i0 + CI + ((c & 2) ? TILE - 1 : 0));
    float dx = xr - cx, dy = yr - cy;
    float rx = cx + P.cosT * dx + P.sinT * dy;
    float ry = cy - P.sinT * dx + P.cosT * dy;
    rxmin = fminf(rxmin, rx); rxmax = fmaxf(rxmax, rx);
    rymin = fminf(rymin, ry); rymax = fmaxf(rymax, ry);
  }
  float xnlo = floorf(rxmin), xnhi = floorf(rxmax) + 1.0f;
  float ynlo = floorf(rymin), ynhi = floorf(rymax) + 1.0f;
  float pxmin = 1e30f, pxmax = -1e30f, pymin = 1e30f, pymax = -1e30f;
#pragma unroll
  for (int c = 0; c < 4; ++c) {
    float xo = (c & 1) ? xnhi : xnlo;
    float yo = (c & 2) ? ynhi : ynlo;
    float inv = 1.0f / (P.g * xo + P.h * yo + 1.0f);
    float px = (P.a * xo + P.b * yo + P.c) * inv;
    float py = (P.d * xo + P.e * yo + P.f) * inv;
    pxmin = fminf(pxmin, px); pxmax = fmaxf(pxmax, px);
    pymin = fminf(pymin, py); pymax = fmaxf(pymax, py);
  }
  int bx0 = max(0, (int)floorf(pxmin));
  int bx1 = min(WW - 1, (int)floorf(pxmax) + 1);
  int by0 = max(0, (int)floorf(pymin));
  int by1 = min(HH - 1, (int)floorf(pymax) + 1);
  int bw = bx1 - bx0 + 1;
  int bh = by1 - by0 + 1;
  bool use_lds = (bw <= BMAXW && bh <= BMAXH);

  int tid = threadIdx.x;
  int i = i0 + (tid >> 4);
  int j = j0 + (tid & 15);
  int opix = i * CROP + j;

  if (use_lds) {
    int pofs[4]; float wts[16];
    make_patches(i, j, P, by0, bx0, bh, bw, pofs, wts);
    for (int s = tid; s < 2 * LWORDS; s += 256)
      ((float*)s_img)[s] = 0.0f;
    __syncthreads();
    {
      const float* xb = xin + (size_t)ch0 * CH_STRIDE;
      const float* nb = nin + (size_t)ch0 * CH_STRIDE;
      int r = tid >> 5, c = tid & 31;
#pragma unroll
      for (int rr = 0; rr < 5; ++rr) {
        int rcur = r + rr * 8;
        if (rcur < bh && c < bw) {
          int g = (by0 + rcur) * WW + bx0 + c;
          s_img[0][(rcur + 1) * LSTR + (c + 1)] = preproc(xb[g], nb[g]);
        }
      }
      if (bw > 32) {
        int r2 = tid >> 2, c2 = 32 + (tid & 3);
        if (r2 < bh && c2 < bw) {
          int g = (by0 + r2) * WW + bx0 + c2;
          s_img[0][(r2 + 1) * LSTR + (c2 + 1)] = preproc(xb[g], nb[g]);
        }
      }
      __syncthreads();
    }
    int buf = 0;
    int r = tid >> 5, c = tid & 31;
    int r2 = tid >> 2, c2 = 32 + (tid & 3);
    for (int cc = 0; cc < GCH; ++cc) {
      int ch = ch0 + cc;
      bool more = (cc < GCH - 1);
      float xv[5], nv[5], xe = 0.0f, ne = 0.0f;
      if (more) {
        const float* xb = xin + (size_t)(ch + 1) * CH_STRIDE;
        const float* nb = nin + (size_t)(ch + 1) * CH_STRIDE;
#pragma unroll
        for (int rr = 0; rr < 5; ++rr) {
          int rcur = r + rr * 8;
          if (rcur < bh && c < bw) {
            int g = (by0 + rcur) * WW + bx0 + c;
            xv[rr] = xb[g]; nv[rr] = nb[g];
          }
        }
        if (bw > 32 && r2 < bh && c2 < bw) {
          int g = (by0 + r2) * WW + bx0 + c2;
          xe = xb[g]; ne = nb[g];
        }
      }
      const float* sb = s_img[buf];
      float acc = 0.0f;
#pragma unroll
      for (int n = 0; n < 4; ++n) {
        int p = pofs[n];
        acc = fmaf(wts[n * 4 + 0], sb[p], acc);
        acc = fmaf(wts[n * 4 + 1], sb[p + 1], acc);
        acc = fmaf(wts[n * 4 + 2], sb[p + LSTR], acc);
        acc = fmaf(wts[n * 4 + 3], sb[p + LSTR + 1], acc);
      }
      crop[(size_t)ch * CROP_STRIDE + opix] = acc;
      if (more) {
        float* sw = s_img[buf ^ 1];
#pragma unroll
        for (int rr = 0; rr < 5; ++rr) {
          int rcur = r + rr * 8;
          if (rcur < bh && c < bw)
            sw[(rcur + 1) * LSTR + (c + 1)] = preproc(xv[rr], nv[rr]);
        }
        if (bw > 32 && r2 < bh && c2 < bw)
          sw[(r2 + 1) * LSTR + (c2 + 1)] = preproc(xe, ne);
      }
      __syncthreads();
      buf ^= 1;
    }
  } else {
    int txs[16], tys[16]; float wts[16];
    make_taps(i, j, P, txs, tys, wts);
    for (int cc = 0; cc < GCH; ++cc) {
      int ch = ch0 + cc;
      const float* xb = xin + (size_t)ch * CH_STRIDE;
      const float* nb = nin + (size_t)ch * CH_STRIDE;
      float acc = 0.0f;
#pragma unroll
      for (int t = 0; t < 16; ++t) {
        int g = tys[t] * WW + txs[t];
        acc = fmaf(wts[t], preproc(xb[g], nb[g]), acc);
      }
      crop[(size_t)ch * CROP_STRIDE + opix] = acc;
    }
  }
}

// ---------------------------------------------------------------------------
// Resize: separable bicubic 160->224, strip per (channel, 28 rows).
// Table computed in-kernel into LDS.
// ---------------------------------------------------------------------------
#define STRIPROWS 28
#define HROWS 25
__global__ __launch_bounds__(256) void resize_strips_kernel(
    const float* __restrict__ crop, float* __restrict__ out) {
  __shared__ float hbuf[HROWS * WW];
  __shared__ float4 swt[HH];
  __shared__ int4 sit[HH];
  int s = blockIdx.x;
  int ch = blockIdx.y;
  int r0 = max(0, s * 20 - 2);
  const float* cb = crop + (size_t)ch * CROP_STRIDE;
  int tid = threadIdx.x;

  if (tid < HH) {
    float w[4]; int id[4];
    axis_weights(tid, w, id);
    swt[tid] = make_float4(w[0], w[1], w[2], w[3]);
    sit[tid] = make_int4(id[0], id[1], id[2], id[3]);
  }
  __syncthreads();

  for (int e = tid; e < HROWS * WW; e += 256) {
    int r = e / WW;
    int xo = e - r * WW;
    int cr = min(r0 + r, CROP - 1);
    float4 wx = swt[xo]; int4 ix = sit[xo];
    const float* row = cb + cr * CROP;
    hbuf[e] = wx.x * row[ix.x] + wx.y * row[ix.y] +
              wx.z * row[ix.z] + wx.w * row[ix.w];
  }
  __syncthreads();
  for (int e = tid; e < STRIPROWS * WW; e += 256) {
    int yl = e / WW;
    int xo = e - yl * WW;
    int yo = s * STRIPROWS + yl;
    float4 wy = swt[yo]; int4 iy = sit[yo];
    float o = wy.x * hbuf[(iy.x - r0) * WW + xo] +
              wy.y * hbuf[(iy.y - r0) * WW + xo] +
              wy.z * hbuf[(iy.z - r0) * WW + xo] +
              wy.w * hbuf[(iy.w - r0) * WW + xo];
    __builtin_nontemporal_store(o, &out[((size_t)ch * HH + yo) * WW + xo]);
  }
}

// ---------------------------------------------------------------------------
// Fully fused fallback (tiny ws).
// ---------------------------------------------------------------------------
__device__ float crop_val(const float* __restrict__ xb, const float* __restrict__ nb,
                          int i, int j, AugParams P) {
  int txs[16], tys[16]; float wts[16];
  make_taps(i, j, P, txs, tys, wts);
  float acc = 0.0f;
#pragma unroll
  for (int t = 0; t < 16; ++t)
    acc = fmaf(wts[t], preproc(xb[tys[t] * WW + txs[t]], nb[tys[t] * WW + txs[t]]), acc);
  return acc;
}

__global__ __launch_bounds__(256) void fused_fallback_kernel(
    const float* __restrict__ xin, const float* __restrict__ nin,
    float* __restrict__ out, AugParams P, int total) {
  int stride = gridDim.x * blockDim.x;
  for (int idx = blockIdx.x * blockDim.x + threadIdx.x; idx < total; idx += stride) {
    int xo = idx % WW;
    int t2 = idx / WW;
    int yo = t2 % HH;
    int ch = t2 / HH;
    float wxa[4]; int ixa[4]; axis_weights(xo, wxa, ixa);
    float wya[4]; int iya[4]; axis_weights(yo, wya, iya);
    const float* xb = xin + (size_t)ch * CH_STRIDE;
    const float* nb = nin + (size_t)ch * CH_STRIDE;
    float acc = 0.0f;
#pragma unroll
    for (int ty = 0; ty < 4; ++ty)
#pragma unroll
      for (int tx = 0; tx < 4; ++tx)
        acc += wya[ty] * wxa[tx] * crop_val(xb, nb, iya[ty], ixa[tx], P);
    out[idx] = acc;
  }
}

// ---------------------------------------------------------------------------
// Host: solve 8x8 perspective system.
// ---------------------------------------------------------------------------
static void solve_coeffs(double C[8]) {
  const double sp[4][2] = {{0, 0}, {223, 0}, {223, 223}, {0, 223}};
  const double ep[4][2] = {{30, 20}, {200, 25}, {210, 200}, {15, 190}};
  double A[8][9];
  for (int k = 0; k < 4; ++k) {
    double xi = sp[k][0], yi = sp[k][1], xo = ep[k][0], yo = ep[k][1];
    double r0[9] = {xo, yo, 1, 0, 0, 0, -xo * xi, -yo * xi, xi};
    double r1[9] = {0, 0, 0, xo, yo, 1, -xo * yi, -yo * yi, yi};
    std::memcpy(A[2 * k], r0, sizeof r0);
    std::memcpy(A[2 * k + 1], r1, sizeof r1);
  }
  for (int col = 0; col < 8; ++col) {
    int piv = col;
    for (int r = col + 1; r < 8; ++r)
      if (std::fabs(A[r][col]) > std::fabs(A[piv][col])) piv = r;
    if (piv != col)
      for (int cc = 0; cc < 9; ++cc) { double t = A[col][cc]; A[col][cc] = A[piv][cc]; A[piv][cc] = t; }
    double p = A[col][col];
    for (int r = 0; r < 8; ++r) {
      if (r == col) continue;
      double fmul = A[r][col] / p;
      for (int cc = col; cc < 9; ++cc) A[r][cc] -= fmul * A[col][cc];
    }
  }
  for (int r = 0; r < 8; ++r) C[r] = A[r][8] / A[r][r];
}

extern "C" void kernel_launch(void* const* d_in, const int* in_sizes, int n_in,
                              void* d_out, int out_size, void* d_ws, size_t ws_size,
                              hipStream_t stream) {
  const float* xin = (const float*)d_in[0];
  const float* nin = (const float*)d_in[1];
  float* out = (float*)d_out;

  double C[8];
  solve_coeffs(C);
  AugParams P;
  P.a = (float)C[0]; P.b = (float)C[1]; P.c = (float)C[2]; P.d = (float)C[3];
  P.e = (float)C[4]; P.f = (float)C[5]; P.g = (float)C[6]; P.h = (float)C[7];
  double t = 10.0 * M_PI / 180.0;
  P.cosT = (float)std::cos(t);
  P.sinT = (float)std::sin(t);

  const int total = NCH * HH * WW;                 // 19,267,584
  const size_t PRE_BYTES = (size_t)NCH * CH_STRIDE * 2;      // 38,535,168
  const size_t CROP_BYTES = (size_t)NCH * CROP_STRIDE * 4;   // 39,321,600
  const size_t need_full = PRE_BYTES + CROP_BYTES;
  const size_t need_med = CROP_BYTES;

  if (ws_size >= need_full) {
    unsigned short* pre = (unsigned short*)d_ws;
    float* crop = (float*)((char*)d_ws + PRE_BYTES);

    hipLaunchKernelGGL(preproc_kernel, dim3(4704), dim3(256), 0, stream,
                       (const float4*)xin, (const float4*)nin, (ushort8*)pre);
    dim3 g1(NTIL2 * NTIL2, NCH / GCH2);            // (25, 48)
    hipLaunchKernelGGL(warp_pre_kernel, g1, dim3(256), 0, stream, pre, crop, P);
    dim3 g2(HH / STRIPROWS, NCH);                  // (8, 384)
    hipLaunchKernelGGL(resize_strips_kernel, g2, dim3(256), 0, stream, crop, out);
  } else if (ws_size >= need_med) {
    float* crop = (float*)d_ws;

    dim3 g1(NTIL * NTIL, NCH / GCH);               // (100, 48)
    hipLaunchKernelGGL(warp_direct_kernel, g1, dim3(256), 0, stream, xin, nin, crop, P);
    dim3 g2(HH / STRIPROWS, NCH);
    hipLaunchKernelGGL(resize_strips_kernel, g2, dim3(256), 0, stream, crop, out);
  } else {
    hipLaunchKernelGGL(fused_fallback_kernel, dim3(2048), dim3(256), 0, stream,
                       xin, nin, out, P, total);
  }
}